// Round 6
// baseline (793.067 us; speedup 1.0000x reference)
//
#include <hip/hip_runtime.h>
#include <hip/hip_bf16.h>
#include <math.h>

typedef __bf16 bf16_t;
typedef __bf16 bf16x4 __attribute__((ext_vector_type(4)));
typedef __bf16 bf16x8 __attribute__((ext_vector_type(8)));
typedef float f32x4 __attribute__((ext_vector_type(4)));

#define SCALE_F 0.08838834764831845f  // 1/sqrt(128)
#define SMAX_F 14.0f                  // fixed softmax max: score <= sqrt(128)=11.32 (+bf16 margin)

// async global->LDS, 16B per lane; LDS dest = wave-uniform base + lane*16
#define GLOAD_LDS16(gp, lp)                                              \
    __builtin_amdgcn_global_load_lds(                                    \
        (const __attribute__((address_space(1))) void*)(gp),             \
        (__attribute__((address_space(3))) void*)(lp), 16, 0, 0)

// ---------------- fp32 -> bf16 convert (vectorized) ----------------
__global__ void k_convert(const float* __restrict__ in, bf16_t* __restrict__ out, int n) {
    int i = (blockIdx.x * 256 + threadIdx.x) * 4;
    if (i >= n) return;
    float4 f = *(const float4*)(in + i);
    out[i + 0] = (bf16_t)f.x;
    out[i + 1] = (bf16_t)f.y;
    out[i + 2] = (bf16_t)f.z;
    out[i + 3] = (bf16_t)f.w;
}

// ---------------- transpose + convert: w[K][N] -> wt[N][K] bf16 ----------------
__global__ void k_transpose(const float* __restrict__ w, bf16_t* __restrict__ wt, int K, int N) {
    __shared__ float tile[32][33];
    int n0 = blockIdx.x * 32, k0 = blockIdx.y * 32;
    int tx = threadIdx.x & 31, ty = threadIdx.x >> 5;  // 32x8
#pragma unroll
    for (int i = 0; i < 32; i += 8)
        tile[ty + i][tx] = w[(size_t)(k0 + ty + i) * N + (n0 + tx)];
    __syncthreads();
#pragma unroll
    for (int i = 0; i < 32; i += 8)
        wt[(size_t)(n0 + ty + i) * K + (k0 + tx)] = (bf16_t)tile[tx][ty + i];
}

// ---------------- rope tables ----------------
__global__ void k_rope_tables(float* __restrict__ cosT, float* __restrict__ sinT) {
    int idx = blockIdx.x * 256 + threadIdx.x;  // t*64 + i
    int t = idx >> 6, i = idx & 63;
    float invf = powf(10000.f, -(float)(i & 31) / 32.f);
    float ang = (float)t * invf;
    float s, c;
    sincosf(ang, &s, &c);
    cosT[idx] = c;
    sinT[idx] = s;
}

// ---------------- row-wise rmsnorm, in-place bf16, fp32 gain ----------------
__global__ void k_rmsnorm(bf16_t* __restrict__ x, const float* __restrict__ g, int C) {
    bf16_t* p = x + (size_t)blockIdx.x * C;
    float ss = 0.f;
    for (int i = threadIdx.x; i < C; i += 256) {
        float v = (float)p[i];
        ss += v * v;
    }
#pragma unroll
    for (int m = 32; m; m >>= 1) ss += __shfl_xor(ss, m);
    __shared__ float red[4];
    if ((threadIdx.x & 63) == 0) red[threadIdx.x >> 6] = ss;
    __syncthreads();
    float tot = red[0] + red[1] + red[2] + red[3];
    float scale = rsqrtf(tot / (float)C + 1e-6f);
    for (int i = threadIdx.x; i < C; i += 256)
        p[i] = (bf16_t)((float)p[i] * scale * g[i]);
}

// ---------------- GEMM (m97 structure, BK=64): C[M][N] = A[M][K] @ Bt[N][K]^T ------
// Two m97-style 32-wide sub-buffers per barrier pair: same LDS read patterns as the
// proven 874-TF kernel, but one barrier pair per K=64 (halves barrier/vmcnt drains).
template <int OUTF32>
__global__ __launch_bounds__(256) void k_gemm(const bf16_t* __restrict__ A,
                                              const bf16_t* __restrict__ Bt,
                                              void* __restrict__ Cp, int M, int N, int K,
                                              size_t sA, size_t sB, size_t sC) {
    __shared__ bf16_t As[2][128 * 32];
    __shared__ bf16_t Bs[2][128 * 32];
    A += (size_t)blockIdx.z * sA;
    Bt += (size_t)blockIdx.z * sB;
    const size_t coff = (size_t)blockIdx.z * sC;
    const int bm = blockIdx.y * 128, bn = blockIdx.x * 128;
    const int tid = threadIdx.x, lane = tid & 63, wv = tid >> 6;
    const int quad = lane >> 4, l16 = lane & 15;
    const int wm = (wv >> 1) * 64, wn = (wv & 1) * 64;
    f32x4 acc[4][4] = {};
    const int sr0 = wv * 32 + (lane >> 2);
    const int scc = (lane & 3) * 8;
    const int lo0 = (wv * 2) * 512, lo1 = (wv * 2 + 1) * 512;
    const bool bok0 = (bn + sr0) < N;
    const bool bok1 = (bn + sr0 + 16) < N;
    for (int k0 = 0; k0 < K; k0 += 64) {
        const bf16_t* gA = A + (size_t)(bm + sr0) * K + k0 + scc;
        const bf16_t* gB = Bt + (size_t)(bn + sr0) * K + k0 + scc;
        GLOAD_LDS16(gA, As[0] + lo0);
        GLOAD_LDS16(gA + (size_t)16 * K, As[0] + lo1);
        GLOAD_LDS16(gA + 32, As[1] + lo0);
        GLOAD_LDS16(gA + (size_t)16 * K + 32, As[1] + lo1);
        if (bok0) {
            GLOAD_LDS16(gB, Bs[0] + lo0);
            GLOAD_LDS16(gB + 32, Bs[1] + lo0);
        }
        if (bok1) {
            GLOAD_LDS16(gB + (size_t)16 * K, Bs[0] + lo1);
            GLOAD_LDS16(gB + (size_t)16 * K + 32, Bs[1] + lo1);
        }
        __syncthreads();
#pragma unroll
        for (int hf = 0; hf < 2; ++hf) {
            bf16x8 af[4], bfr[4];
#pragma unroll
            for (int mi = 0; mi < 4; ++mi)
                af[mi] = *(bf16x8*)(As[hf] + (wm + mi * 16 + l16) * 32 + quad * 8);
#pragma unroll
            for (int ni = 0; ni < 4; ++ni)
                bfr[ni] = *(bf16x8*)(Bs[hf] + (wn + ni * 16 + l16) * 32 + quad * 8);
#pragma unroll
            for (int mi = 0; mi < 4; ++mi)
#pragma unroll
                for (int ni = 0; ni < 4; ++ni)
                    acc[mi][ni] = __builtin_amdgcn_mfma_f32_16x16x32_bf16(af[mi], bfr[ni],
                                                                          acc[mi][ni], 0, 0, 0);
        }
        __syncthreads();
    }
#pragma unroll
    for (int mi = 0; mi < 4; ++mi)
#pragma unroll
        for (int ni = 0; ni < 4; ++ni)
#pragma unroll
            for (int r = 0; r < 4; ++r) {
                int row = bm + wm + mi * 16 + quad * 4 + r;
                int col = bn + wn + ni * 16 + l16;
                if (col < N) {
                    if constexpr (OUTF32)
                        ((float*)Cp)[coff + (size_t)row * N + col] = acc[mi][ni][r];
                    else
                        ((bf16_t*)Cp)[coff + (size_t)row * N + col] = (bf16_t)acc[mi][ni][r];
                }
            }
}

// ---------------- build q ----------------
__global__ void k_build_q(bf16_t* __restrict__ q, const float* __restrict__ g,
                          const float* __restrict__ cosT, const float* __restrict__ sinT) {
    int wid = blockIdx.x * 4 + (threadIdx.x >> 6);
    int lane = threadIdx.x & 63;
    int row = wid >> 4, h = wid & 15;
    int t = row & 2047;
    bf16_t* p = q + (size_t)row * 2048 + h * 128;
    float x0 = (float)p[lane];
    float x1 = (float)p[64 + lane];
    float xp = (float)p[64 + (lane ^ 32)];
    float c = cosT[t * 64 + lane], s = sinT[t * 64 + lane];
    float rot = (lane < 32) ? -xp : xp;
    float y1 = x1 * c + rot * s;
    float ss = x0 * x0 + y1 * y1;
#pragma unroll
    for (int m = 32; m; m >>= 1) ss += __shfl_xor(ss, m);
    float scale = rsqrtf(ss / 128.f + 1e-6f);
    p[lane] = (bf16_t)(x0 * scale * g[lane]);
    p[64 + lane] = (bf16_t)(y1 * scale * g[64 + lane]);
}

// ---------------- build k ----------------
__global__ void k_build_k(const bf16_t* __restrict__ knope, const bf16_t* __restrict__ krope,
                          bf16_t* __restrict__ kout, const float* __restrict__ g,
                          const float* __restrict__ cosT, const float* __restrict__ sinT) {
    int wid = blockIdx.x * 4 + (threadIdx.x >> 6);
    int lane = threadIdx.x & 63;
    int row = wid >> 4, h = wid & 15;
    int t = row & 2047;
    float x0 = (float)knope[(size_t)row * 1024 + h * 64 + lane];
    float x1 = (float)krope[(size_t)row * 64 + lane];
    float xp = (float)krope[(size_t)row * 64 + (lane ^ 32)];
    float c = cosT[t * 64 + lane], s = sinT[t * 64 + lane];
    float rot = (lane < 32) ? -xp : xp;
    float y1 = x1 * c + rot * s;
    float ss = x0 * x0 + y1 * y1;
#pragma unroll
    for (int m = 32; m; m >>= 1) ss += __shfl_xor(ss, m);
    float scale = rsqrtf(ss / 128.f + 1e-6f);
    bf16_t* p = kout + (size_t)row * 2048 + h * 128;
    p[lane] = (bf16_t)(x0 * scale * g[lane]);
    p[64 + lane] = (bf16_t)(y1 * scale * g[64 + lane]);
}

// ---------------- flash attention + silu(gate), swapped-QK, 32 rows/wave ----------
// grid (T/128, B*H), 256 threads = 4 waves; wave wv owns q-rows [t0+32wv, +32) as two
// 16-row tiles (mi=0,1). Every Ks/Vt LDS fragment read feeds 2 MFMAs -> per-tile LDS
// reads HALVED vs the 16-row/wave version (R5 was stall-bound: all pipes <30%).
// QK^T SWAPPED: mfma(A=K, B=Q[mi]); lane(quad,l16) holds S[s0+16ni+4quad+r][wrow+16mi+l16].
// Softmax per-lane; P stays in registers (pa[mi][kh]); V stored s-bit-permuted
//   s = 32kk+16b4+4q+lo2  ->  p = 32kk+8q+4b4+lo2
// so PV contracts A and B in the same permuted k-order (image identical to R5's,
// which was harness-verified). l: deferred per-lane partials + shfl + lbuf transpose.
// Register budget ~165; __launch_bounds__(256,2) (cap 256 -> no spill possible).
// q,k,gate,o layout [(b*2048+pos)*2048 + h*128 + d]; vT layout [b][h*128+d][t].
__global__ __launch_bounds__(256, 2) void k_attn(const bf16_t* __restrict__ q,
                                                 const bf16_t* __restrict__ k,
                                                 const bf16_t* __restrict__ vT,
                                                 const bf16_t* __restrict__ gate,
                                                 bf16_t* __restrict__ o) {
    __shared__ bf16_t Ks[64 * 136];   // [s][128 d +8]       17.4 KB
    __shared__ bf16_t Vt[128 * 72];   // [d][64 s-perm +8]   18.4 KB
    __shared__ float lbuf[128];       // l broadcast          0.5 KB
    const int qb = (int)gridDim.x - 1 - (int)blockIdx.x;  // long blocks first
    const int bh = blockIdx.y;
    const int b = bh >> 4, h = bh & 15;
    const int t0 = qb * 128;
    const int tid = threadIdx.x, lane = tid & 63, wv = tid >> 6;  // wv 0..3
    const int quad = lane >> 4, l16 = lane & 15;
    const int wrow = t0 + wv * 32;  // wave's first q row

    // Q B-fragments in registers: 2 row-tiles x 4 k-slices
    bf16x8 aq[2][4];
#pragma unroll
    for (int mi = 0; mi < 2; ++mi) {
        const bf16_t* qp =
            q + ((size_t)(b * 2048 + wrow + mi * 16 + l16)) * 2048 + h * 128 + quad * 8;
#pragma unroll
        for (int kk = 0; kk < 4; ++kk) aq[mi][kk] = *(const bf16x8*)(qp + kk * 32);
    }
    f32x4 oacc[2][8] = {};   // [row-tile][d-tile]
    float l_lane[2] = {0.f, 0.f};

    const bf16_t* vbase = vT + ((size_t)b * 2048 + (size_t)h * 128) * 2048;
    const bf16_t* kbase = k + ((size_t)b * 2048) * 2048 + h * 128;

    // staging indices (256 threads)
    const int krow = tid >> 4;          // 0..15 (+16,+32,+48)
    const int kcol = (tid & 15) * 8;
    const int kds = krow * 136 + kcol;
    const int vrow = tid >> 1;          // 0..127 (one d-row per 2 threads)
    const int vkk = tid & 1;            // which 32-s half this thread permutes
    const int vds = vrow * 72 + vkk * 32;

    const int nkb = 2 * qb + 2;  // key tiles 0 .. 2qb+1
    bf16x8 kreg[4], vreg[4];
    {
#pragma unroll
        for (int i = 0; i < 4; ++i)
            kreg[i] = *(const bf16x8*)(kbase + (size_t)(krow + 16 * i) * 2048 + kcol);
#pragma unroll
        for (int j = 0; j < 4; ++j)
            vreg[j] = *(const bf16x8*)(vbase + (size_t)vrow * 2048 + vkk * 32 + j * 8);
    }
    for (int kb = 0; kb < nkb; ++kb) {
        const int s0 = kb * 64;
        __syncthreads();  // prev iter done reading Ks/Vt
#pragma unroll
        for (int i = 0; i < 4; ++i) *(bf16x8*)(Ks + kds + i * (16 * 136)) = kreg[i];
        {
            // permuted V writes: p-chunk m gets [vreg[m>>1][(m&1)*4..], vreg[2+(m>>1)][(m&1)*4..]]
            bf16x8 o0 = __builtin_shufflevector(vreg[0], vreg[2], 0, 1, 2, 3, 8, 9, 10, 11);
            bf16x8 o1 = __builtin_shufflevector(vreg[0], vreg[2], 4, 5, 6, 7, 12, 13, 14, 15);
            bf16x8 o2 = __builtin_shufflevector(vreg[1], vreg[3], 0, 1, 2, 3, 8, 9, 10, 11);
            bf16x8 o3 = __builtin_shufflevector(vreg[1], vreg[3], 4, 5, 6, 7, 12, 13, 14, 15);
            *(bf16x8*)(Vt + vds) = o0;
            *(bf16x8*)(Vt + vds + 8) = o1;
            *(bf16x8*)(Vt + vds + 16) = o2;
            *(bf16x8*)(Vt + vds + 24) = o3;
        }
        __syncthreads();
        if (kb + 1 < nkb) {  // prefetch next tile; latency overlaps compute below
            const int sn = s0 + 64;
#pragma unroll
            for (int i = 0; i < 4; ++i)
                kreg[i] = *(const bf16x8*)(kbase + (size_t)(sn + krow + 16 * i) * 2048 + kcol);
#pragma unroll
            for (int j = 0; j < 4; ++j)
                vreg[j] = *(const bf16x8*)(vbase + (size_t)vrow * 2048 + sn + vkk * 32 + j * 8);
        }
        if (s0 > wrow + 31) continue;  // wave fully above diagonal (wave-uniform skip)
        // S^T = K Q^T for both row-tiles; softmax in-register; pa assembled on the fly
        const int tq0 = wrow + l16;
        const int tq1 = wrow + 16 + l16;
        bf16x8 pa[2][2];  // [row-tile][s-half kh]; filled across ni iterations
#pragma unroll
        for (int ni = 0; ni < 4; ++ni) {
            f32x4 sc0 = {0.f, 0.f, 0.f, 0.f};
            f32x4 sc1 = {0.f, 0.f, 0.f, 0.f};
#pragma unroll
            for (int kk = 0; kk < 4; ++kk) {
                bf16x8 ak = *(bf16x8*)(Ks + (ni * 16 + l16) * 136 + kk * 32 + quad * 8);
                sc0 = __builtin_amdgcn_mfma_f32_16x16x32_bf16(ak, aq[0][kk], sc0, 0, 0, 0);
                sc1 = __builtin_amdgcn_mfma_f32_16x16x32_bf16(ak, aq[1][kk], sc1, 0, 0, 0);
            }
            const int sb = s0 + ni * 16 + quad * 4;
#pragma unroll
            for (int r2 = 0; r2 < 4; ++r2) {
                float pv0 = __expf(sc0[r2] * SCALE_F - SMAX_F);
                float pv1 = __expf(sc1[r2] * SCALE_F - SMAX_F);
                if (sb + r2 > tq0) pv0 = 0.f;
                if (sb + r2 > tq1) pv1 = 0.f;
                l_lane[0] += pv0;
                l_lane[1] += pv1;
                pa[0][ni >> 1][(ni & 1) * 4 + r2] = (bf16_t)pv0;
                pa[1][ni >> 1][(ni & 1) * 4 + r2] = (bf16_t)pv1;
            }
        }
        // O += P V : each bv read feeds both row-tiles
#pragma unroll
        for (int kh = 0; kh < 2; ++kh)
#pragma unroll
            for (int nd = 0; nd < 8; ++nd) {
                bf16x8 bv = *(bf16x8*)(Vt + (nd * 16 + l16) * 72 + kh * 32 + quad * 8);
                oacc[0][nd] =
                    __builtin_amdgcn_mfma_f32_16x16x32_bf16(pa[0][kh], bv, oacc[0][nd], 0, 0, 0);
                oacc[1][nd] =
                    __builtin_amdgcn_mfma_f32_16x16x32_bf16(pa[1][kh], bv, oacc[1][nd], 0, 0, 0);
            }
    }
    // finish l: sum the 4 quads holding each t, broadcast via wave-private lbuf
#pragma unroll
    for (int mi = 0; mi < 2; ++mi) {
        l_lane[mi] += __shfl_xor(l_lane[mi], 16);
        l_lane[mi] += __shfl_xor(l_lane[mi], 32);
    }
    if (quad == 0) {
        lbuf[wv * 32 + l16] = l_lane[0];
        lbuf[wv * 32 + 16 + l16] = l_lane[1];
    }
    float rl[2][4];
#pragma unroll
    for (int mi = 0; mi < 2; ++mi)
#pragma unroll
        for (int r2 = 0; r2 < 4; ++r2)
            rl[mi][r2] = 1.f / lbuf[wv * 32 + mi * 16 + quad * 4 + r2];
    // epilogue: normalize, silu(gate), store
#pragma unroll
    for (int mi = 0; mi < 2; ++mi)
#pragma unroll
        for (int nd = 0; nd < 8; ++nd) {
            int d = nd * 16 + l16;
#pragma unroll
            for (int r2 = 0; r2 < 4; ++r2) {
                int trow = wrow + mi * 16 + quad * 4 + r2;
                size_t gi = ((size_t)(b * 2048 + trow)) * 2048 + h * 128 + d;
                float gt = (float)gate[gi];
                float sg = gt / (1.f + __expf(-gt));
                o[gi] = (bf16_t)((oacc[mi][nd][r2] * rl[mi][r2]) * sg);
            }
        }
}

extern "C" void kernel_launch(void* const* d_in, const int* in_sizes, int n_in,
                              void* d_out, int out_size, void* d_ws, size_t ws_size,
                              hipStream_t stream) {
    const float* x         = (const float*)d_in[0];
    const float* w_q_down  = (const float*)d_in[1];
    const float* g_q_down  = (const float*)d_in[2];
    const float* w_q_up    = (const float*)d_in[3];
    const float* w_kv_down = (const float*)d_in[4];
    const float* g_kv_down = (const float*)d_in[5];
    const float* w_k_up    = (const float*)d_in[6];
    const float* w_v_up    = (const float*)d_in[7];
    const float* w_k_rope  = (const float*)d_in[8];
    const float* g_q       = (const float*)d_in[9];
    const float* g_k       = (const float*)d_in[10];
    const float* w_gate    = (const float*)d_in[11];
    const float* w_o       = (const float*)d_in[12];
    float* out = (float*)d_out;

    char* base = (char*)d_ws;
    size_t off = 0;
    auto alloc = [&](size_t bytes) -> void* {
        void* p = base + off;
        off = (off + bytes + 255) & ~(size_t)255;
        return p;
    };
    const size_t MT = 8192;  // B*T
    bf16_t* xb     = (bf16_t*)alloc(MT * 2048 * 2);
    bf16_t* wqd_t  = (bf16_t*)alloc((size_t)1024 * 2048 * 2);
    bf16_t* wqu_t  = (bf16_t*)alloc((size_t)2048 * 1024 * 2);
    bf16_t* wkvd_t = (bf16_t*)alloc((size_t)512 * 2048 * 2);
    bf16_t* wku_t  = (bf16_t*)alloc((size_t)1024 * 512 * 2);
    bf16_t* wvu_t  = (bf16_t*)alloc((size_t)2048 * 512 * 2);
    bf16_t* wkr_t  = (bf16_t*)alloc((size_t)64 * 2048 * 2);
    bf16_t* wg_t   = (bf16_t*)alloc((size_t)2048 * 2048 * 2);
    bf16_t* wo_t   = (bf16_t*)alloc((size_t)2048 * 2048 * 2);
    bf16_t* qc     = (bf16_t*)alloc(MT * 1024 * 2);
    bf16_t* ckv    = (bf16_t*)alloc(MT * 512 * 2);
    bf16_t* krope  = (bf16_t*)alloc(MT * 64 * 2);
    bf16_t* vT     = (bf16_t*)alloc(MT * 2048 * 2);  // [b][h*128+d][t]
    bf16_t* gbuf   = (bf16_t*)alloc(MT * 2048 * 2);
    float* cosT    = (float*)alloc((size_t)2048 * 64 * 4);
    float* sinT    = (float*)alloc((size_t)2048 * 64 * 4);
    bf16_t* knope = qc;              // qc dead after q_up GEMM
    bf16_t* qbuf  = (bf16_t*)d_out;  // d_out scratch until final GEMM
    bf16_t* kbuf  = (bf16_t*)d_out + MT * 2048;
    bf16_t* obuf  = xb;              // xb dead after all x@W GEMMs

    k_convert<<<dim3(16384), dim3(256), 0, stream>>>(x, xb, 16777216);
    k_transpose<<<dim3(32, 64), 256, 0, stream>>>(w_q_down, wqd_t, 2048, 1024);
    k_transpose<<<dim3(64, 32), 256, 0, stream>>>(w_q_up, wqu_t, 1024, 2048);
    k_transpose<<<dim3(16, 64), 256, 0, stream>>>(w_kv_down, wkvd_t, 2048, 512);
    k_transpose<<<dim3(32, 16), 256, 0, stream>>>(w_k_up, wku_t, 512, 1024);
    k_transpose<<<dim3(64, 16), 256, 0, stream>>>(w_v_up, wvu_t, 512, 2048);
    k_transpose<<<dim3(2, 64), 256, 0, stream>>>(w_k_rope, wkr_t, 2048, 64);
    k_transpose<<<dim3(64, 64), 256, 0, stream>>>(w_gate, wg_t, 2048, 2048);
    k_transpose<<<dim3(64, 64), 256, 0, stream>>>(w_o, wo_t, 2048, 2048);
    k_rope_tables<<<dim3(512), 256, 0, stream>>>(cosT, sinT);
    // q path
    k_gemm<0><<<dim3(8, 64), 256, 0, stream>>>(xb, wqd_t, qc, 8192, 1024, 2048, 0, 0, 0);
    k_rmsnorm<<<dim3(8192), 256, 0, stream>>>(qc, g_q_down, 1024);
    k_gemm<0><<<dim3(16, 64), 256, 0, stream>>>(qc, wqu_t, qbuf, 8192, 2048, 1024, 0, 0, 0);
    // kv path
    k_gemm<0><<<dim3(4, 64), 256, 0, stream>>>(xb, wkvd_t, ckv, 8192, 512, 2048, 0, 0, 0);
    k_rmsnorm<<<dim3(8192), 256, 0, stream>>>(ckv, g_kv_down, 512);
    k_gemm<0><<<dim3(8, 64), 256, 0, stream>>>(ckv, wku_t, knope, 8192, 1024, 512, 0, 0, 0);
    // V^T per batch: vT_b[hd][t] = wvu_t[hd][k] · ckv_b[t][k]
    k_gemm<0><<<dim3(16, 16, 4), 256, 0, stream>>>(wvu_t, ckv, vT, 2048, 2048, 512,
                                                   0, (size_t)2048 * 512, (size_t)2048 * 2048);
    k_gemm<0><<<dim3(1, 64), 256, 0, stream>>>(xb, wkr_t, krope, 8192, 64, 2048, 0, 0, 0);
    // gate
    k_gemm<0><<<dim3(16, 64), 256, 0, stream>>>(xb, wg_t, gbuf, 8192, 2048, 2048, 0, 0, 0);
    // assemble q/k
    k_build_q<<<dim3(32768), 256, 0, stream>>>(qbuf, g_q, cosT, sinT);
    k_build_k<<<dim3(32768), 256, 0, stream>>>(knope, krope, kbuf, g_k, cosT, sinT);
    // attention + silu(gate)
    k_attn<<<dim3(16, 64), 256, 0, stream>>>(qbuf, kbuf, vT, gbuf, obuf);
    // output projection
    k_gemm<1><<<dim3(16, 64), 256, 0, stream>>>(obuf, wo_t, out, 8192, 2048, 2048, 0, 0, 0);
}

// Round 8
// 705.412 us; speedup vs baseline: 1.1243x; 1.1243x over previous
//
#include <hip/hip_runtime.h>
#include <hip/hip_bf16.h>
#include <math.h>

typedef __bf16 bf16_t;
typedef __bf16 bf16x4 __attribute__((ext_vector_type(4)));
typedef __bf16 bf16x8 __attribute__((ext_vector_type(8)));
typedef float f32x4 __attribute__((ext_vector_type(4)));

#define SCALE_F 0.08838834764831845f  // 1/sqrt(128)
#define SMAX_F 14.0f                  // fixed softmax max: score <= sqrt(128)=11.32 (+bf16 margin)

// async global->LDS, 16B per lane; LDS dest = wave-uniform base + lane*16
#define GLOAD_LDS16(gp, lp)                                              \
    __builtin_amdgcn_global_load_lds(                                    \
        (const __attribute__((address_space(1))) void*)(gp),             \
        (__attribute__((address_space(3))) void*)(lp), 16, 0, 0)

// ---------------- fp32 -> bf16 convert (vectorized) ----------------
__global__ void k_convert(const float* __restrict__ in, bf16_t* __restrict__ out, int n) {
    int i = (blockIdx.x * 256 + threadIdx.x) * 4;
    if (i >= n) return;
    float4 f = *(const float4*)(in + i);
    out[i + 0] = (bf16_t)f.x;
    out[i + 1] = (bf16_t)f.y;
    out[i + 2] = (bf16_t)f.z;
    out[i + 3] = (bf16_t)f.w;
}

// ---------------- transpose + convert: w[K][N] -> wt[N][K] bf16 ----------------
__global__ void k_transpose(const float* __restrict__ w, bf16_t* __restrict__ wt, int K, int N) {
    __shared__ float tile[32][33];
    int n0 = blockIdx.x * 32, k0 = blockIdx.y * 32;
    int tx = threadIdx.x & 31, ty = threadIdx.x >> 5;  // 32x8
#pragma unroll
    for (int i = 0; i < 32; i += 8)
        tile[ty + i][tx] = w[(size_t)(k0 + ty + i) * N + (n0 + tx)];
    __syncthreads();
#pragma unroll
    for (int i = 0; i < 32; i += 8)
        wt[(size_t)(n0 + ty + i) * K + (k0 + tx)] = (bf16_t)tile[tx][ty + i];
}

// ---------------- rope tables ----------------
__global__ void k_rope_tables(float* __restrict__ cosT, float* __restrict__ sinT) {
    int idx = blockIdx.x * 256 + threadIdx.x;  // t*64 + i
    int t = idx >> 6, i = idx & 63;
    float invf = powf(10000.f, -(float)(i & 31) / 32.f);
    float ang = (float)t * invf;
    float s, c;
    sincosf(ang, &s, &c);
    cosT[idx] = c;
    sinT[idx] = s;
}

// ---------------- row-wise rmsnorm, in-place bf16, fp32 gain ----------------
__global__ void k_rmsnorm(bf16_t* __restrict__ x, const float* __restrict__ g, int C) {
    bf16_t* p = x + (size_t)blockIdx.x * C;
    float ss = 0.f;
    for (int i = threadIdx.x; i < C; i += 256) {
        float v = (float)p[i];
        ss += v * v;
    }
#pragma unroll
    for (int m = 32; m; m >>= 1) ss += __shfl_xor(ss, m);
    __shared__ float red[4];
    if ((threadIdx.x & 63) == 0) red[threadIdx.x >> 6] = ss;
    __syncthreads();
    float tot = red[0] + red[1] + red[2] + red[3];
    float scale = rsqrtf(tot / (float)C + 1e-6f);
    for (int i = threadIdx.x; i < C; i += 256)
        p[i] = (bf16_t)((float)p[i] * scale * g[i]);
}

// ---------------- GEMM (m97 structure, BK=64): C[M][N] = A[M][K] @ Bt[N][K]^T ------
// Two m97-style 32-wide sub-buffers per barrier pair: same LDS read patterns as the
// proven 874-TF kernel, but one barrier pair per K=64 (halves barrier/vmcnt drains).
template <int OUTF32>
__global__ __launch_bounds__(256) void k_gemm(const bf16_t* __restrict__ A,
                                              const bf16_t* __restrict__ Bt,
                                              void* __restrict__ Cp, int M, int N, int K,
                                              size_t sA, size_t sB, size_t sC) {
    __shared__ bf16_t As[2][128 * 32];
    __shared__ bf16_t Bs[2][128 * 32];
    A += (size_t)blockIdx.z * sA;
    Bt += (size_t)blockIdx.z * sB;
    const size_t coff = (size_t)blockIdx.z * sC;
    const int bm = blockIdx.y * 128, bn = blockIdx.x * 128;
    const int tid = threadIdx.x, lane = tid & 63, wv = tid >> 6;
    const int quad = lane >> 4, l16 = lane & 15;
    const int wm = (wv >> 1) * 64, wn = (wv & 1) * 64;
    f32x4 acc[4][4] = {};
    const int sr0 = wv * 32 + (lane >> 2);
    const int scc = (lane & 3) * 8;
    const int lo0 = (wv * 2) * 512, lo1 = (wv * 2 + 1) * 512;
    const bool bok0 = (bn + sr0) < N;
    const bool bok1 = (bn + sr0 + 16) < N;
    for (int k0 = 0; k0 < K; k0 += 64) {
        const bf16_t* gA = A + (size_t)(bm + sr0) * K + k0 + scc;
        const bf16_t* gB = Bt + (size_t)(bn + sr0) * K + k0 + scc;
        GLOAD_LDS16(gA, As[0] + lo0);
        GLOAD_LDS16(gA + (size_t)16 * K, As[0] + lo1);
        GLOAD_LDS16(gA + 32, As[1] + lo0);
        GLOAD_LDS16(gA + (size_t)16 * K + 32, As[1] + lo1);
        if (bok0) {
            GLOAD_LDS16(gB, Bs[0] + lo0);
            GLOAD_LDS16(gB + 32, Bs[1] + lo0);
        }
        if (bok1) {
            GLOAD_LDS16(gB + (size_t)16 * K, Bs[0] + lo1);
            GLOAD_LDS16(gB + (size_t)16 * K + 32, Bs[1] + lo1);
        }
        __syncthreads();
#pragma unroll
        for (int hf = 0; hf < 2; ++hf) {
            bf16x8 af[4], bfr[4];
#pragma unroll
            for (int mi = 0; mi < 4; ++mi)
                af[mi] = *(bf16x8*)(As[hf] + (wm + mi * 16 + l16) * 32 + quad * 8);
#pragma unroll
            for (int ni = 0; ni < 4; ++ni)
                bfr[ni] = *(bf16x8*)(Bs[hf] + (wn + ni * 16 + l16) * 32 + quad * 8);
#pragma unroll
            for (int mi = 0; mi < 4; ++mi)
#pragma unroll
                for (int ni = 0; ni < 4; ++ni)
                    acc[mi][ni] = __builtin_amdgcn_mfma_f32_16x16x32_bf16(af[mi], bfr[ni],
                                                                          acc[mi][ni], 0, 0, 0);
        }
        __syncthreads();
    }
#pragma unroll
    for (int mi = 0; mi < 4; ++mi)
#pragma unroll
        for (int ni = 0; ni < 4; ++ni)
#pragma unroll
            for (int r = 0; r < 4; ++r) {
                int row = bm + wm + mi * 16 + quad * 4 + r;
                int col = bn + wn + ni * 16 + l16;
                if (col < N) {
                    if constexpr (OUTF32)
                        ((float*)Cp)[coff + (size_t)row * N + col] = acc[mi][ni][r];
                    else
                        ((bf16_t*)Cp)[coff + (size_t)row * N + col] = (bf16_t)acc[mi][ni][r];
                }
            }
}

// ---------------- build q ----------------
__global__ void k_build_q(bf16_t* __restrict__ q, const float* __restrict__ g,
                          const float* __restrict__ cosT, const float* __restrict__ sinT) {
    int wid = blockIdx.x * 4 + (threadIdx.x >> 6);
    int lane = threadIdx.x & 63;
    int row = wid >> 4, h = wid & 15;
    int t = row & 2047;
    bf16_t* p = q + (size_t)row * 2048 + h * 128;
    float x0 = (float)p[lane];
    float x1 = (float)p[64 + lane];
    float xp = (float)p[64 + (lane ^ 32)];
    float c = cosT[t * 64 + lane], s = sinT[t * 64 + lane];
    float rot = (lane < 32) ? -xp : xp;
    float y1 = x1 * c + rot * s;
    float ss = x0 * x0 + y1 * y1;
#pragma unroll
    for (int m = 32; m; m >>= 1) ss += __shfl_xor(ss, m);
    float scale = rsqrtf(ss / 128.f + 1e-6f);
    p[lane] = (bf16_t)(x0 * scale * g[lane]);
    p[64 + lane] = (bf16_t)(y1 * scale * g[64 + lane]);
}

// ---------------- build k ----------------
__global__ void k_build_k(const bf16_t* __restrict__ knope, const bf16_t* __restrict__ krope,
                          bf16_t* __restrict__ kout, const float* __restrict__ g,
                          const float* __restrict__ cosT, const float* __restrict__ sinT) {
    int wid = blockIdx.x * 4 + (threadIdx.x >> 6);
    int lane = threadIdx.x & 63;
    int row = wid >> 4, h = wid & 15;
    int t = row & 2047;
    float x0 = (float)knope[(size_t)row * 1024 + h * 64 + lane];
    float x1 = (float)krope[(size_t)row * 64 + lane];
    float xp = (float)krope[(size_t)row * 64 + (lane ^ 32)];
    float c = cosT[t * 64 + lane], s = sinT[t * 64 + lane];
    float rot = (lane < 32) ? -xp : xp;
    float y1 = x1 * c + rot * s;
    float ss = x0 * x0 + y1 * y1;
#pragma unroll
    for (int m = 32; m; m >>= 1) ss += __shfl_xor(ss, m);
    float scale = rsqrtf(ss / 128.f + 1e-6f);
    bf16_t* p = kout + (size_t)row * 2048 + h * 128;
    p[lane] = (bf16_t)(x0 * scale * g[lane]);
    p[64 + lane] = (bf16_t)(y1 * scale * g[64 + lane]);
}

// ---------------- flash attention + silu(gate), swapped-QK, dbuf K/V LDS ----------
// grid (16,64) relabeled XCD-aware: lin = bx+16*by; xcd = lin&7; all 16 q-blocks of a
// head stay on one XCD's L2 (K/V reuse). 256 threads = 4 waves x 32 q-rows.
// DOUBLE-BUFFERED K/V LDS, ONE barrier per tile (R6 was stall-bound: 2 barriers +
// serial LDS-write burst per tile, all pipes <27%). Invariant at iter kb: buf[kb&1]
// ready, regs hold tile kb+1. Body: write tile kb+1 -> buf[kb&1^1] (disjoint from
// readers), issue loads tile kb+2, compute from buf[kb&1], barrier.
// QK^T SWAPPED: mfma(A=K, B=Q[mi]); lane(quad,l16) holds S[s0+16ni+4quad+r][wrow+16mi+l16].
// Softmax per-lane in-register (__expf; masking hoisted to diagonal tiles only);
// P stays in registers. V stored s-bit-permuted
// (s=32kk+16b4+4q+lo2 -> p=32kk+8q+4b4+lo2) so PV contracts in permuted k-order
// (image identical to R5/R6, harness-verified).
// q,k,gate,o layout [(b*2048+pos)*2048 + h*128 + d]; vT layout [b][h*128+d][t].
__global__ __launch_bounds__(256, 2) void k_attn(const bf16_t* __restrict__ q,
                                                 const bf16_t* __restrict__ k,
                                                 const bf16_t* __restrict__ vT,
                                                 const bf16_t* __restrict__ gate,
                                                 bf16_t* __restrict__ o) {
    __shared__ bf16_t Ks[2][64 * 136];   // [s][128 d +8]       2x17.4 KB
    __shared__ bf16_t Vt[2][128 * 72];   // [d][64 s-perm +8]   2x18.4 KB
    __shared__ float lbuf[128];          // l broadcast          0.5 KB
    const int lin = (int)blockIdx.x + 16 * (int)blockIdx.y;  // 0..1023
    const int xcd = lin & 7, idx = lin >> 3;
    const int bh = xcd * 8 + (idx & 7);
    const int qb = 15 - (idx >> 3);  // long blocks first within each XCD stream
    const int b = bh >> 4, h = bh & 15;
    const int t0 = qb * 128;
    const int tid = threadIdx.x, lane = tid & 63, wv = tid >> 6;  // wv 0..3
    const int quad = lane >> 4, l16 = lane & 15;
    const int wrow = t0 + wv * 32;  // wave's first q row

    // Q B-fragments in registers: 2 row-tiles x 4 k-slices
    bf16x8 aq[2][4];
#pragma unroll
    for (int mi = 0; mi < 2; ++mi) {
        const bf16_t* qp =
            q + ((size_t)(b * 2048 + wrow + mi * 16 + l16)) * 2048 + h * 128 + quad * 8;
#pragma unroll
        for (int kk = 0; kk < 4; ++kk) aq[mi][kk] = *(const bf16x8*)(qp + kk * 32);
    }
    f32x4 oacc[2][8] = {};   // [row-tile][d-tile]
    float l_lane[2] = {0.f, 0.f};

    const bf16_t* vbase = vT + ((size_t)b * 2048 + (size_t)h * 128) * 2048;
    const bf16_t* kbase = k + ((size_t)b * 2048) * 2048 + h * 128;

    // staging indices (256 threads)
    const int krow = tid >> 4;          // 0..15 (+16,+32,+48)
    const int kcol = (tid & 15) * 8;
    const int kds = krow * 136 + kcol;
    const int vrow = tid >> 1;          // 0..127 (one d-row per 2 threads)
    const int vkk = tid & 1;            // which 32-s half this thread permutes
    const int vds = vrow * 72 + vkk * 32;

    const int nkb = 2 * qb + 2;  // key tiles 0 .. 2qb+1
    bf16x8 kreg[4], vreg[4];
    auto LOADREGS = [&](int sn) {
#pragma unroll
        for (int i = 0; i < 4; ++i)
            kreg[i] = *(const bf16x8*)(kbase + (size_t)(sn + krow + 16 * i) * 2048 + kcol);
#pragma unroll
        for (int j = 0; j < 4; ++j)
            vreg[j] = *(const bf16x8*)(vbase + (size_t)vrow * 2048 + sn + vkk * 32 + j * 8);
    };
    auto STAGE = [&](int buf) {
#pragma unroll
        for (int i = 0; i < 4; ++i) *(bf16x8*)(Ks[buf] + kds + i * (16 * 136)) = kreg[i];
        // permuted V writes: p-chunk m gets [vreg[m>>1][(m&1)*4..], vreg[2+(m>>1)][(m&1)*4..]]
        bf16x8 o0 = __builtin_shufflevector(vreg[0], vreg[2], 0, 1, 2, 3, 8, 9, 10, 11);
        bf16x8 o1 = __builtin_shufflevector(vreg[0], vreg[2], 4, 5, 6, 7, 12, 13, 14, 15);
        bf16x8 o2 = __builtin_shufflevector(vreg[1], vreg[3], 0, 1, 2, 3, 8, 9, 10, 11);
        bf16x8 o3 = __builtin_shufflevector(vreg[1], vreg[3], 4, 5, 6, 7, 12, 13, 14, 15);
        *(bf16x8*)(Vt[buf] + vds) = o0;
        *(bf16x8*)(Vt[buf] + vds + 8) = o1;
        *(bf16x8*)(Vt[buf] + vds + 16) = o2;
        *(bf16x8*)(Vt[buf] + vds + 24) = o3;
    };
    // prologue: tile 0 staged into buf0; tile 1 loads in flight
    LOADREGS(0);
    STAGE(0);
    LOADREGS(64);
    __syncthreads();

    for (int kb = 0; kb < nkb; ++kb) {
        const int s0 = kb * 64;
        const int cur = kb & 1;
        if (kb + 1 < nkb) {
            STAGE(cur ^ 1);                       // write tile kb+1 (overlaps compute)
            if (kb + 2 < nkb) LOADREGS((kb + 2) * 64);  // issue loads tile kb+2
        }
        if (s0 <= wrow + 31) {
            const bf16_t* ksp = Ks[cur];
            const bf16_t* vtp = Vt[cur];
            const int tq0 = wrow + l16;
            const int tq1 = wrow + 16 + l16;
            const bool dgw = (s0 + 63 > wrow);  // wave-uniform: any masking needed
            bf16x8 pa[2][2];  // [row-tile][s-half kh]; filled across ni iterations
#pragma unroll
            for (int ni = 0; ni < 4; ++ni) {
                f32x4 sc0 = {0.f, 0.f, 0.f, 0.f};
                f32x4 sc1 = {0.f, 0.f, 0.f, 0.f};
#pragma unroll
                for (int kk = 0; kk < 4; ++kk) {
                    bf16x8 ak = *(bf16x8*)(ksp + (ni * 16 + l16) * 136 + kk * 32 + quad * 8);
                    sc0 = __builtin_amdgcn_mfma_f32_16x16x32_bf16(ak, aq[0][kk], sc0, 0, 0, 0);
                    sc1 = __builtin_amdgcn_mfma_f32_16x16x32_bf16(ak, aq[1][kk], sc1, 0, 0, 0);
                }
                const int sb = s0 + ni * 16 + quad * 4;
                if (dgw) {
#pragma unroll
                    for (int r2 = 0; r2 < 4; ++r2) {
                        float pv0 = __expf(sc0[r2] * SCALE_F - SMAX_F);
                        float pv1 = __expf(sc1[r2] * SCALE_F - SMAX_F);
                        if (sb + r2 > tq0) pv0 = 0.f;
                        if (sb + r2 > tq1) pv1 = 0.f;
                        l_lane[0] += pv0;
                        l_lane[1] += pv1;
                        pa[0][ni >> 1][(ni & 1) * 4 + r2] = (bf16_t)pv0;
                        pa[1][ni >> 1][(ni & 1) * 4 + r2] = (bf16_t)pv1;
                    }
                } else {
#pragma unroll
                    for (int r2 = 0; r2 < 4; ++r2) {
                        float pv0 = __expf(sc0[r2] * SCALE_F - SMAX_F);
                        float pv1 = __expf(sc1[r2] * SCALE_F - SMAX_F);
                        l_lane[0] += pv0;
                        l_lane[1] += pv1;
                        pa[0][ni >> 1][(ni & 1) * 4 + r2] = (bf16_t)pv0;
                        pa[1][ni >> 1][(ni & 1) * 4 + r2] = (bf16_t)pv1;
                    }
                }
            }
            // O += P V : each bv read feeds both row-tiles
#pragma unroll
            for (int kh = 0; kh < 2; ++kh)
#pragma unroll
                for (int nd = 0; nd < 8; ++nd) {
                    bf16x8 bv = *(bf16x8*)(vtp + (nd * 16 + l16) * 72 + kh * 32 + quad * 8);
                    oacc[0][nd] = __builtin_amdgcn_mfma_f32_16x16x32_bf16(pa[0][kh], bv,
                                                                          oacc[0][nd], 0, 0, 0);
                    oacc[1][nd] = __builtin_amdgcn_mfma_f32_16x16x32_bf16(pa[1][kh], bv,
                                                                          oacc[1][nd], 0, 0, 0);
                }
        }
        __syncthreads();
    }
    // finish l: sum the 4 quads holding each t, broadcast via wave-private lbuf
#pragma unroll
    for (int mi = 0; mi < 2; ++mi) {
        l_lane[mi] += __shfl_xor(l_lane[mi], 16);
        l_lane[mi] += __shfl_xor(l_lane[mi], 32);
    }
    if (quad == 0) {
        lbuf[wv * 32 + l16] = l_lane[0];
        lbuf[wv * 32 + 16 + l16] = l_lane[1];
    }
    float rl[2][4];
#pragma unroll
    for (int mi = 0; mi < 2; ++mi)
#pragma unroll
        for (int r2 = 0; r2 < 4; ++r2)
            rl[mi][r2] = 1.f / lbuf[wv * 32 + mi * 16 + quad * 4 + r2];
    // epilogue: normalize, silu(gate), store
#pragma unroll
    for (int mi = 0; mi < 2; ++mi)
#pragma unroll
        for (int nd = 0; nd < 8; ++nd) {
            int d = nd * 16 + l16;
#pragma unroll
            for (int r2 = 0; r2 < 4; ++r2) {
                int trow = wrow + mi * 16 + quad * 4 + r2;
                size_t gi = ((size_t)(b * 2048 + trow)) * 2048 + h * 128 + d;
                float gt = (float)gate[gi];
                float sg = gt / (1.f + __expf(-gt));
                o[gi] = (bf16_t)((oacc[mi][nd][r2] * rl[mi][r2]) * sg);
            }
        }
}

extern "C" void kernel_launch(void* const* d_in, const int* in_sizes, int n_in,
                              void* d_out, int out_size, void* d_ws, size_t ws_size,
                              hipStream_t stream) {
    const float* x         = (const float*)d_in[0];
    const float* w_q_down  = (const float*)d_in[1];
    const float* g_q_down  = (const float*)d_in[2];
    const float* w_q_up    = (const float*)d_in[3];
    const float* w_kv_down = (const float*)d_in[4];
    const float* g_kv_down = (const float*)d_in[5];
    const float* w_k_up    = (const float*)d_in[6];
    const float* w_v_up    = (const float*)d_in[7];
    const float* w_k_rope  = (const float*)d_in[8];
    const float* g_q       = (const float*)d_in[9];
    const float* g_k       = (const float*)d_in[10];
    const float* w_gate    = (const float*)d_in[11];
    const float* w_o       = (const float*)d_in[12];
    float* out = (float*)d_out;

    char* base = (char*)d_ws;
    size_t off = 0;
    auto alloc = [&](size_t bytes) -> void* {
        void* p = base + off;
        off = (off + bytes + 255) & ~(size_t)255;
        return p;
    };
    const size_t MT = 8192;  // B*T
    bf16_t* xb     = (bf16_t*)alloc(MT * 2048 * 2);
    bf16_t* wqd_t  = (bf16_t*)alloc((size_t)1024 * 2048 * 2);
    bf16_t* wqu_t  = (bf16_t*)alloc((size_t)2048 * 1024 * 2);
    bf16_t* wkvd_t = (bf16_t*)alloc((size_t)512 * 2048 * 2);
    bf16_t* wku_t  = (bf16_t*)alloc((size_t)1024 * 512 * 2);
    bf16_t* wvu_t  = (bf16_t*)alloc((size_t)2048 * 512 * 2);
    bf16_t* wkr_t  = (bf16_t*)alloc((size_t)64 * 2048 * 2);
    bf16_t* wg_t   = (bf16_t*)alloc((size_t)2048 * 2048 * 2);
    bf16_t* wo_t   = (bf16_t*)alloc((size_t)2048 * 2048 * 2);
    bf16_t* qc     = (bf16_t*)alloc(MT * 1024 * 2);
    bf16_t* ckv    = (bf16_t*)alloc(MT * 512 * 2);
    bf16_t* krope  = (bf16_t*)alloc(MT * 64 * 2);
    bf16_t* vT     = (bf16_t*)alloc(MT * 2048 * 2);  // [b][h*128+d][t]
    bf16_t* gbuf   = (bf16_t*)alloc(MT * 2048 * 2);
    float* cosT    = (float*)alloc((size_t)2048 * 64 * 4);
    float* sinT    = (float*)alloc((size_t)2048 * 64 * 4);
    bf16_t* knope = qc;              // qc dead after q_up GEMM
    bf16_t* qbuf  = (bf16_t*)d_out;  // d_out scratch until final GEMM
    bf16_t* kbuf  = (bf16_t*)d_out + MT * 2048;
    bf16_t* obuf  = xb;              // xb dead after all x@W GEMMs

    k_convert<<<dim3(16384), dim3(256), 0, stream>>>(x, xb, 16777216);
    k_transpose<<<dim3(32, 64), 256, 0, stream>>>(w_q_down, wqd_t, 2048, 1024);
    k_transpose<<<dim3(64, 32), 256, 0, stream>>>(w_q_up, wqu_t, 1024, 2048);
    k_transpose<<<dim3(16, 64), 256, 0, stream>>>(w_kv_down, wkvd_t, 2048, 512);
    k_transpose<<<dim3(32, 16), 256, 0, stream>>>(w_k_up, wku_t, 512, 1024);
    k_transpose<<<dim3(64, 16), 256, 0, stream>>>(w_v_up, wvu_t, 512, 2048);
    k_transpose<<<dim3(2, 64), 256, 0, stream>>>(w_k_rope, wkr_t, 2048, 64);
    k_transpose<<<dim3(64, 64), 256, 0, stream>>>(w_gate, wg_t, 2048, 2048);
    k_transpose<<<dim3(64, 64), 256, 0, stream>>>(w_o, wo_t, 2048, 2048);
    k_rope_tables<<<dim3(512), 256, 0, stream>>>(cosT, sinT);
    // q path
    k_gemm<0><<<dim3(8, 64), 256, 0, stream>>>(xb, wqd_t, qc, 8192, 1024, 2048, 0, 0, 0);
    k_rmsnorm<<<dim3(8192), 256, 0, stream>>>(qc, g_q_down, 1024);
    k_gemm<0><<<dim3(16, 64), 256, 0, stream>>>(qc, wqu_t, qbuf, 8192, 2048, 1024, 0, 0, 0);
    // kv path
    k_gemm<0><<<dim3(4, 64), 256, 0, stream>>>(xb, wkvd_t, ckv, 8192, 512, 2048, 0, 0, 0);
    k_rmsnorm<<<dim3(8192), 256, 0, stream>>>(ckv, g_kv_down, 512);
    k_gemm<0><<<dim3(8, 64), 256, 0, stream>>>(ckv, wku_t, knope, 8192, 1024, 512, 0, 0, 0);
    // V^T per batch: vT_b[hd][t] = wvu_t[hd][k] · ckv_b[t][k]
    k_gemm<0><<<dim3(16, 16, 4), 256, 0, stream>>>(wvu_t, ckv, vT, 2048, 2048, 512,
                                                   0, (size_t)2048 * 512, (size_t)2048 * 2048);
    k_gemm<0><<<dim3(1, 64), 256, 0, stream>>>(xb, wkr_t, krope, 8192, 64, 2048, 0, 0, 0);
    // gate
    k_gemm<0><<<dim3(16, 64), 256, 0, stream>>>(xb, wg_t, gbuf, 8192, 2048, 2048, 0, 0, 0);
    // assemble q/k
    k_build_q<<<dim3(32768), 256, 0, stream>>>(qbuf, g_q, cosT, sinT);
    k_build_k<<<dim3(32768), 256, 0, stream>>>(knope, krope, kbuf, g_k, cosT, sinT);
    // attention + silu(gate)
    k_attn<<<dim3(16, 64), 256, 0, stream>>>(qbuf, kbuf, vT, gbuf, obuf);
    // output projection
    k_gemm<1><<<dim3(16, 64), 256, 0, stream>>>(obuf, wo_t, out, 8192, 2048, 2048, 0, 0, 0);
}